// Round 6
// baseline (971.907 us; speedup 1.0000x reference)
//
#include <hip/hip_runtime.h>
#include <stdint.h>

// out[b,s,o] = sum_i x[b,s,i] * (W[o,i] + sum_r A[o,r]*B[r,i]) + bias[o]
// M = 16384, N = 4096, K = 4096. fp32 in/out, bf16 MFMA compute.
// GEMM: 256x256 tile, BK=64, 8 waves, 8-phase schedule.
// R6: one-phase read-ahead (register double-buffer of ds_reads) so each
//     phase's LDS drain overlaps the previous phase's MFMA; balanced
//     4/8 reads per phase; uniform stage->read distance 4 with vmcnt(6).

#define MDIM 16384
#define NDIM 4096
#define KDIM 4096
#define RANK 16
#define NT   (KDIM / 64)   // 64 K-tiles

typedef __bf16  bf16x8 __attribute__((ext_vector_type(8)));
typedef float   f32x4  __attribute__((ext_vector_type(4)));
typedef unsigned short u16x8 __attribute__((ext_vector_type(8)));

__device__ __forceinline__ unsigned short f2bf(float f) {
  union { float f; uint32_t u; } v; v.f = f;
  uint32_t r = v.u + 0x7FFFu + ((v.u >> 16) & 1u);
  return (unsigned short)(r >> 16);
}

__device__ __forceinline__ void gl16(const void* g, void* l) {
  __builtin_amdgcn_global_load_lds(
      (__attribute__((address_space(1))) void*)(g),
      (__attribute__((address_space(3))) void*)(l),
      16, 0, 0);
}

// Wp[o][i] = bf16(W[o][i] + sum_r A[o][r]*B[r][i])
__global__ void prep_w(const float* __restrict__ W, const float* __restrict__ A,
                       const float* __restrict__ Bm, unsigned short* __restrict__ Wp) {
  const int i = blockIdx.x * 256 + threadIdx.x;
  const int o = blockIdx.y;
  float acc = W[(size_t)o * NDIM + i];
#pragma unroll
  for (int r = 0; r < RANK; ++r)
    acc += A[o * RANK + r] * Bm[(size_t)r * NDIM + i];
  Wp[(size_t)o * NDIM + i] = f2bf(acc);
}

// x fp32 -> bf16, 8 elems/thread
__global__ void cast_x(const float* __restrict__ x, unsigned short* __restrict__ xb) {
  const size_t i = ((size_t)blockIdx.x * 256 + threadIdx.x) * 8;
  float4 a = *(const float4*)(x + i);
  float4 b = *(const float4*)(x + i + 4);
  u16x8 o;
  o[0] = f2bf(a.x); o[1] = f2bf(a.y); o[2] = f2bf(a.z); o[3] = f2bf(a.w);
  o[4] = f2bf(b.x); o[5] = f2bf(b.y); o[6] = f2bf(b.z); o[7] = f2bf(b.w);
  *(u16x8*)(xb + i) = o;
}

#define BARRIER  __builtin_amdgcn_s_barrier()
#define VMCNT6   asm volatile("s_waitcnt vmcnt(6)" ::: "memory")
#define VMCNT4   asm volatile("s_waitcnt vmcnt(4)" ::: "memory")
#define WAITVM0  asm volatile("s_waitcnt vmcnt(0)" ::: "memory")
#define SCHEDB   __builtin_amdgcn_sched_barrier(0)

// ---- staging: one half-tile (128 LDS rows) = 2 x gl16 per thread ----
// A LDS layout: row = mh*128 + wm*64 + (mi*16+lr).
#define STAGE_A(buf, h, kt) do {                                              \
    const int kc_ = ((kt) < NT ? (kt) : NT - 1);                              \
    const unsigned short* g_ = agb + (size_t)((h) * 64) * KDIM + kc_ * 64;    \
    unsigned short* d_ = &sA[(buf)][0] + (h) * 8192 + t * 8;                  \
    gl16(g_, d_);                                                             \
    gl16(g_ + (size_t)128 * KDIM, d_ + 4096);                                 \
  } while (0)

// B LDS layout: row = nh*128 + wn*32 + (ni*16+lr).
#define STAGE_B(buf, h, kt) do {                                              \
    const int kc_ = ((kt) < NT ? (kt) : NT - 1);                              \
    const unsigned short* g_ = bgb + (size_t)((h) * 32) * KDIM + kc_ * 64;    \
    unsigned short* d_ = &sB[(buf)][0] + (h) * 8192 + t * 8;                  \
    gl16(g_, d_);                                                             \
    gl16(g_ + (size_t)128 * KDIM, d_ + 4096);                                 \
  } while (0)

// ds_read fragments into an explicit register set (read-ahead).
#define LDA_TO(dst, buf, mh) do {                                             \
    _Pragma("unroll") for (int mi = 0; mi < 4; ++mi)                          \
    _Pragma("unroll") for (int kk = 0; kk < 2; ++kk)                          \
      dst[mi][kk] = *(const bf16x8*)(saw + (buf)*16384 + ((mh)*128 + mi*16)*64\
                                     + ((kk*32 + koff) ^ xorE));              \
  } while (0)

#define LDB_TO(dst, buf, nh) do {                                             \
    _Pragma("unroll") for (int ni = 0; ni < 2; ++ni)                          \
    _Pragma("unroll") for (int kk = 0; kk < 2; ++kk)                          \
      dst[ni][kk] = *(const bf16x8*)(sbw + (buf)*16384 + ((nh)*128 + ni*16)*64\
                                     + ((kk*32 + koff) ^ xorE));              \
  } while (0)

#define MMQ(mh, nh, aS, bS) do {                                              \
    __builtin_amdgcn_s_setprio(1);                                            \
    _Pragma("unroll") for (int mi = 0; mi < 4; ++mi)                          \
    _Pragma("unroll") for (int ni = 0; ni < 2; ++ni)                          \
    _Pragma("unroll") for (int kk = 0; kk < 2; ++kk)                          \
      acc[(mh)*4+mi][(nh)*2+ni] = __builtin_amdgcn_mfma_f32_16x16x32_bf16(    \
          aS[mi][kk], bS[ni][kk], acc[(mh)*4+mi][(nh)*2+ni], 0, 0, 0);        \
    __builtin_amdgcn_s_setprio(0);                                            \
  } while (0)

__global__ __launch_bounds__(512, 2) void gemm256(
    const unsigned short* __restrict__ Xb,
    const unsigned short* __restrict__ Wp,
    const float* __restrict__ bias,
    float* __restrict__ out) {
  __shared__ __align__(16) unsigned short sA[2][256 * 64];  // 64 KiB
  __shared__ __align__(16) unsigned short sB[2][256 * 64];  // 64 KiB

  const int t  = threadIdx.x;
  const int l  = t & 63;
  const int w  = t >> 6;   // 0..7
  const int wm = w >> 2;   // 0..1  (m half: 128 rows)
  const int wn = w & 3;    // 0..3  (n quarter: 64 cols)

  // XCD-aware bijective swizzle; n-fastest: each XCD owns an 8-row bm band.
  const int bid = blockIdx.x;
  const int swz = (bid & 7) * (1024 / 8) + (bid >> 3);
  const int bm  = (swz >> 4) * 256;   // 64 m-tiles
  const int bn  = (swz & 15) * 256;   // 16 n-tiles

  // ---- staging bases ----
  const int sr  = t >> 3;  // LDS-row-within-half 0..63
  const int ske = (((t & 7) * 16) ^ ((sr & 7) << 4)) >> 1;  // bytes -> elems
  const unsigned short* agb = Xb + (size_t)(bm + sr) * KDIM + ske;
  const unsigned short* bgb = Wp + (size_t)(bn + (sr >> 5) * 64 + (sr & 31)) * KDIM + ske;

  // ---- ds_read addressing ----
  const int lr   = l & 15;
  const int koff = (l >> 4) * 8;      // elements
  const int xorE = (lr & 7) << 3;     // elements ((row&7)<<4 bytes)
  const unsigned short* saw = &sA[0][0] + (wm * 64 + lr) * 64;
  const unsigned short* sbw = &sB[0][0] + (wn * 32 + lr) * 64;

  // fragment register sets (read-ahead double buffering)
  bf16x8 aA[4][2], aB[4][2], bX[2][2], bY[2][2], bZ[2][2];
  f32x4 acc[8][4];
#pragma unroll
  for (int i = 0; i < 8; ++i)
#pragma unroll
    for (int j = 0; j < 4; ++j)
      acc[i][j] = f32x4{0.f, 0.f, 0.f, 0.f};

  // ---- prologue: t0 all 4 halves + t1 {B.h0, A.h0} (12 loads);
  //      vmcnt(4) -> t0 landed; barrier; pre-read bX/aA for ph1's MM.
  STAGE_B(0, 0, 0); STAGE_A(0, 0, 0); STAGE_B(0, 1, 0); STAGE_A(0, 1, 0);
  STAGE_B(1, 0, 1); STAGE_A(1, 0, 1);
  VMCNT4;
  BARRIER;
  LDB_TO(bX, 0, 0);
  LDA_TO(aA, 0, 0);

  // ---- main loop: 2 K-tiles / iter, 8 phases.
  // Reads one phase ahead of their MM; stages exactly 4 phases ahead of
  // their first read; vmcnt(6)+barrier every phase = landing guarantee.
  for (int it = 0; it < NT / 2; ++it) {
    const int E = it * 2;
    // ph1: MM(0,0)[aA,bX] ; read bY <- buf0.nh1
    LDB_TO(bY, 0, 1);
    STAGE_B(1, 1, E + 1);
    SCHEDB; BARRIER;
    MMQ(0, 0, aA, bX);
    VMCNT6; BARRIER;
    // ph2: MM(0,1)[aA,bY] ; read aB <- buf0.mh1
    LDA_TO(aB, 0, 1);
    STAGE_A(1, 1, E + 1);
    SCHEDB; BARRIER;
    MMQ(0, 1, aA, bY);
    VMCNT6; BARRIER;
    // ph3: MM(1,1)[aB,bY] ; read bZ <- buf1.nh0
    LDB_TO(bZ, 1, 0);
    STAGE_B(0, 0, E + 2);
    SCHEDB; BARRIER;
    MMQ(1, 1, aB, bY);
    VMCNT6; BARRIER;
    // ph4: MM(1,0)[aB,bX] ; read aA <- buf1.mh0
    LDA_TO(aA, 1, 0);
    STAGE_A(0, 0, E + 2);
    SCHEDB; BARRIER;
    MMQ(1, 0, aB, bX);
    VMCNT6; BARRIER;
    // ph5: MM(0,0)[aA,bZ] ; read bY <- buf1.nh1
    LDB_TO(bY, 1, 1);
    STAGE_B(0, 1, E + 2);
    SCHEDB; BARRIER;
    MMQ(0, 0, aA, bZ);
    VMCNT6; BARRIER;
    // ph6: MM(0,1)[aA,bY] ; read aB <- buf1.mh1
    LDA_TO(aB, 1, 1);
    STAGE_A(0, 1, E + 2);
    SCHEDB; BARRIER;
    MMQ(0, 1, aA, bY);
    VMCNT6; BARRIER;
    // ph7: MM(1,1)[aB,bY] ; read bX <- buf0.nh0 (tile E+2)
    LDB_TO(bX, 0, 0);
    STAGE_B(1, 0, E + 3);
    SCHEDB; BARRIER;
    MMQ(1, 1, aB, bY);
    VMCNT6; BARRIER;
    // ph8: MM(1,0)[aB,bZ] ; read aA <- buf0.mh0 (tile E+2)
    LDA_TO(aA, 0, 0);
    STAGE_A(1, 0, E + 3);
    SCHEDB; BARRIER;
    MMQ(1, 0, aB, bZ);
    VMCNT6; BARRIER;
  }

  WAITVM0;  // drain stray prefetches before LDS dealloc

  // ---- epilogue: C/D layout col=lane&15, row=(lane>>4)*4+reg ----
#pragma unroll
  for (int mf = 0; mf < 8; ++mf) {
#pragma unroll
    for (int nf = 0; nf < 4; ++nf) {
      const int row = bm + wm * 128 + mf * 16 + (l >> 4) * 4;
      const int col = bn + wn * 64 + nf * 16 + lr;
      const float bv = bias[col];
#pragma unroll
      for (int r = 0; r < 4; ++r)
        out[(size_t)(row + r) * NDIM + col] = acc[mf][nf][r] + bv;
    }
  }
}

extern "C" void kernel_launch(void* const* d_in, const int* in_sizes, int n_in,
                              void* d_out, int out_size, void* d_ws, size_t ws_size,
                              hipStream_t stream) {
  const float* x    = (const float*)d_in[0];
  const float* W    = (const float*)d_in[1];
  const float* bias = (const float*)d_in[2];
  const float* A    = (const float*)d_in[3];
  const float* B    = (const float*)d_in[4];
  float* out        = (float*)d_out;

  unsigned short* Wp = (unsigned short*)d_ws;                       // 32 MiB
  unsigned short* Xb = (unsigned short*)d_ws + (size_t)NDIM * KDIM; // 128 MiB

  prep_w<<<dim3(NDIM / 256, NDIM), 256, 0, stream>>>(W, A, B, Wp);
  cast_x<<<dim3((size_t)MDIM * KDIM / (256 * 8)), 256, 0, stream>>>(x, Xb);
  gemm256<<<dim3((MDIM / 256) * (NDIM / 256)), 512, 0, stream>>>(Xb, Wp, bias, out);
}

// Round 7
// 707.961 us; speedup vs baseline: 1.3728x; 1.3728x over previous
//
#include <hip/hip_runtime.h>
#include <stdint.h>

// out[b,s,o] = sum_i x[b,s,i] * (W[o,i] + sum_r A[o,r]*B[r,i]) + bias[o]
// M = 16384, N = 4096, K = 4096. fp32 in/out, bf16 MFMA compute.
// GEMM: 256x256 tile, BK=64, 8 waves, 8-phase schedule (R5 skeleton).
// R7: mfma_f32_32x32x16_bf16 (m119: +14.7% pipe rate, half the MFMA instrs);
//     fused prep kernel (cast_x + prep_w in one launch).

#define MDIM 16384
#define NDIM 4096
#define KDIM 4096
#define RANK 16
#define NT   (KDIM / 64)   // 64 K-tiles

typedef __bf16  bf16x8 __attribute__((ext_vector_type(8)));
typedef float   f32x16 __attribute__((ext_vector_type(16)));
typedef unsigned short u16x8 __attribute__((ext_vector_type(8)));

__device__ __forceinline__ unsigned short f2bf(float f) {
  union { float f; uint32_t u; } v; v.f = f;
  uint32_t r = v.u + 0x7FFFu + ((v.u >> 16) & 1u);
  return (unsigned short)(r >> 16);
}

__device__ __forceinline__ void gl16(const void* g, void* l) {
  __builtin_amdgcn_global_load_lds(
      (__attribute__((address_space(1))) void*)(g),
      (__attribute__((address_space(3))) void*)(l),
      16, 0, 0);
}

// Fused: blocks [0, 32768) cast x fp32->bf16 (8 elems/thread);
//        blocks [32768, 40960) compute Wp = bf16(W + A@B) (8 elems/thread).
#define CAST_BLOCKS 32768
__global__ void prep_fused(const float* __restrict__ x,
                           const float* __restrict__ W,
                           const float* __restrict__ A,
                           const float* __restrict__ Bm,
                           unsigned short* __restrict__ xb,
                           unsigned short* __restrict__ Wp) {
  const int b = blockIdx.x;
  if (b < CAST_BLOCKS) {
    const size_t i = ((size_t)b * 256 + threadIdx.x) * 8;
    float4 a0 = *(const float4*)(x + i);
    float4 a1 = *(const float4*)(x + i + 4);
    u16x8 o;
    o[0] = f2bf(a0.x); o[1] = f2bf(a0.y); o[2] = f2bf(a0.z); o[3] = f2bf(a0.w);
    o[4] = f2bf(a1.x); o[5] = f2bf(a1.y); o[6] = f2bf(a1.z); o[7] = f2bf(a1.w);
    *(u16x8*)(xb + i) = o;
  } else {
    const size_t idx = ((size_t)(b - CAST_BLOCKS) * 256 + threadIdx.x) * 8;
    const int o  = (int)(idx >> 12);        // /4096
    const int i0 = (int)(idx & 4095);
    float accv[8];
    {
      float4 w0 = *(const float4*)(W + (size_t)o * NDIM + i0);
      float4 w1 = *(const float4*)(W + (size_t)o * NDIM + i0 + 4);
      accv[0] = w0.x; accv[1] = w0.y; accv[2] = w0.z; accv[3] = w0.w;
      accv[4] = w1.x; accv[5] = w1.y; accv[6] = w1.z; accv[7] = w1.w;
    }
#pragma unroll
    for (int r = 0; r < RANK; ++r) {
      const float ar = A[o * RANK + r];
      float4 b0 = *(const float4*)(Bm + (size_t)r * NDIM + i0);
      float4 b1 = *(const float4*)(Bm + (size_t)r * NDIM + i0 + 4);
      accv[0] += ar * b0.x; accv[1] += ar * b0.y;
      accv[2] += ar * b0.z; accv[3] += ar * b0.w;
      accv[4] += ar * b1.x; accv[5] += ar * b1.y;
      accv[6] += ar * b1.z; accv[7] += ar * b1.w;
    }
    u16x8 ov;
#pragma unroll
    for (int j = 0; j < 8; ++j) ov[j] = f2bf(accv[j]);
    *(u16x8*)(Wp + idx) = ov;
  }
}

#define BARRIER  __builtin_amdgcn_s_barrier()
#define VMCNT8   asm volatile("s_waitcnt vmcnt(8)" ::: "memory")
#define VMCNT6   asm volatile("s_waitcnt vmcnt(6)" ::: "memory")
#define WAITVM0  asm volatile("s_waitcnt vmcnt(0)" ::: "memory")

// ---- staging: one half-tile (128 LDS rows) = 2 x gl16 per thread ----
// A LDS layout: row = mh*128 + wm*64 + (mi*32 + (l&31)).
#define STAGE_A(buf, h, kt) do {                                              \
    const int kc_ = ((kt) < NT ? (kt) : NT - 1);                              \
    const unsigned short* g_ = agb + (size_t)((h) * 64) * KDIM + kc_ * 64;    \
    unsigned short* d_ = &sA[(buf)][0] + (h) * 8192 + t * 8;                  \
    gl16(g_, d_);                                                             \
    gl16(g_ + (size_t)128 * KDIM, d_ + 4096);                                 \
  } while (0)

// B LDS layout: row = nh*128 + wn*32 + (l&31).
#define STAGE_B(buf, h, kt) do {                                              \
    const int kc_ = ((kt) < NT ? (kt) : NT - 1);                              \
    const unsigned short* g_ = bgb + (size_t)((h) * 32) * KDIM + kc_ * 64;    \
    unsigned short* d_ = &sB[(buf)][0] + (h) * 8192 + t * 8;                  \
    gl16(g_, d_);                                                             \
    gl16(g_ + (size_t)128 * KDIM, d_ + 4096);                                 \
  } while (0)

// ds_read fragments; element k-offset (ks*16 + koff) ^ xorE, xorE=(l&7)<<3.
#define LDA32(buf, mh) do {                                                   \
    _Pragma("unroll") for (int mi = 0; mi < 2; ++mi)                          \
    _Pragma("unroll") for (int ks = 0; ks < 4; ++ks)                          \
      a[mi][ks] = *(const bf16x8*)(saw + (buf)*16384 + ((mh)*128 + mi*32)*64  \
                                   + ((ks*16 + koff) ^ xorE));                \
  } while (0)

#define LDB32(dst, buf, nh) do {                                              \
    _Pragma("unroll") for (int ks = 0; ks < 4; ++ks)                          \
      dst[ks] = *(const bf16x8*)(sbw + (buf)*16384 + ((nh)*128)*64            \
                                 + ((ks*16 + koff) ^ xorE));                  \
  } while (0)

// Interleaved A+B issue (early counted-lgkm MFMA start): b, a0, a1 per ks.
#define LDAB32(buf, mh, nh, dst) do {                                         \
    _Pragma("unroll") for (int ks = 0; ks < 4; ++ks) {                        \
      dst[ks] = *(const bf16x8*)(sbw + (buf)*16384 + ((nh)*128)*64            \
                                 + ((ks*16 + koff) ^ xorE));                  \
      a[0][ks] = *(const bf16x8*)(saw + (buf)*16384 + ((mh)*128)*64           \
                                  + ((ks*16 + koff) ^ xorE));                 \
      a[1][ks] = *(const bf16x8*)(saw + (buf)*16384 + ((mh)*128 + 32)*64      \
                                  + ((ks*16 + koff) ^ xorE));                 \
    }                                                                         \
  } while (0)

#define MM32(mh, nh, bset) do {                                               \
    __builtin_amdgcn_s_setprio(1);                                            \
    _Pragma("unroll") for (int ks = 0; ks < 4; ++ks)                          \
    _Pragma("unroll") for (int mi = 0; mi < 2; ++mi)                          \
      acc[(mh)*2+mi][nh] = __builtin_amdgcn_mfma_f32_32x32x16_bf16(           \
          a[mi][ks], bset[ks], acc[(mh)*2+mi][nh], 0, 0, 0);                  \
    __builtin_amdgcn_s_setprio(0);                                            \
  } while (0)

__global__ __launch_bounds__(512, 2) void gemm256(
    const unsigned short* __restrict__ Xb,
    const unsigned short* __restrict__ Wp,
    const float* __restrict__ bias,
    float* __restrict__ out) {
  __shared__ __align__(16) unsigned short sA[2][256 * 64];  // 64 KiB
  __shared__ __align__(16) unsigned short sB[2][256 * 64];  // 64 KiB

  const int t  = threadIdx.x;
  const int l  = t & 63;
  const int w  = t >> 6;   // 0..7
  const int wm = w >> 2;   // 0..1  (m half: 128 rows)
  const int wn = w & 3;    // 0..3  (n quarter: 64 cols)

  // XCD-aware bijective swizzle; n-fastest: each XCD owns an 8-row bm band.
  const int bid = blockIdx.x;
  const int swz = (bid & 7) * (1024 / 8) + (bid >> 3);
  const int bm  = (swz >> 4) * 256;   // 64 m-tiles
  const int bn  = (swz & 15) * 256;   // 16 n-tiles

  // ---- staging bases ----
  const int sr  = t >> 3;  // LDS-row-within-half 0..63
  const int ske = (((t & 7) * 16) ^ ((sr & 7) << 4)) >> 1;  // bytes -> elems
  const unsigned short* agb = Xb + (size_t)(bm + sr) * KDIM + ske;
  const unsigned short* bgb = Wp + (size_t)(bn + (sr >> 5) * 64 + (sr & 31)) * KDIM + ske;

  // ---- ds_read addressing (32x32 fragments) ----
  const int lc   = l & 31;            // row/col within fragment
  const int koff = (l >> 5) * 8;      // elements
  const int xorE = (l & 7) << 3;      // elements ((row&7)<<4 bytes)
  const unsigned short* saw = &sA[0][0] + (wm * 64 + lc) * 64;
  const unsigned short* sbw = &sB[0][0] + (wn * 32 + lc) * 64;

  bf16x8 a[2][4], b0[4], b1[4];
  f32x16 acc[4][2];
#pragma unroll
  for (int i = 0; i < 4; ++i)
#pragma unroll
    for (int j = 0; j < 2; ++j)
#pragma unroll
      for (int r = 0; r < 16; ++r)
        acc[i][j][r] = 0.f;

  // ---- prologue: tile0 all 4 halves + tile1 {A.h0,B.h0,B.h1} (14 loads);
  //      vmcnt(6) -> tile0 fully landed, tile1's 3 halves in flight.
  STAGE_A(0, 0, 0); STAGE_B(0, 0, 0); STAGE_A(0, 1, 0); STAGE_B(0, 1, 0);
  STAGE_A(1, 0, 1); STAGE_B(1, 0, 1); STAGE_B(1, 1, 1);
  VMCNT6;
  BARRIER;

  // ---- main loop: 2 K-tiles / iter, 8 phases (R5 stage schedule) ----
  for (int it = 0; it < NT / 2; ++it) {
    const int E = it * 2;
    // ph1 (buf0): quadrant 00
    LDAB32(0, 0, 0, b0);
    STAGE_A(1, 1, E + 1);
    BARRIER;
    MM32(0, 0, b0);
    BARRIER;
    // ph2: quadrant 01
    LDB32(b1, 0, 1);
    STAGE_A(0, 0, E + 2);
    BARRIER;
    MM32(0, 1, b1);
    VMCNT8;
    BARRIER;
    // ph3: quadrant 11
    LDA32(0, 1);
    STAGE_B(0, 0, E + 2);
    BARRIER;
    MM32(1, 1, b1);
    BARRIER;
    // ph4: quadrant 10 (no ds_read)
    STAGE_B(0, 1, E + 2);
    BARRIER;
    MM32(1, 0, b0);
    VMCNT8;
    BARRIER;
    // ph5 (buf1): quadrant 00
    LDAB32(1, 0, 0, b0);
    STAGE_A(0, 1, E + 2);
    BARRIER;
    MM32(0, 0, b0);
    BARRIER;
    // ph6: quadrant 01
    LDB32(b1, 1, 1);
    STAGE_A(1, 0, E + 3);
    BARRIER;
    MM32(0, 1, b1);
    VMCNT8;
    BARRIER;
    // ph7: quadrant 11
    LDA32(1, 1);
    STAGE_B(1, 0, E + 3);
    BARRIER;
    MM32(1, 1, b1);
    BARRIER;
    // ph8: quadrant 10
    STAGE_B(1, 1, E + 3);
    BARRIER;
    MM32(1, 0, b0);
    VMCNT8;
    BARRIER;
  }

  WAITVM0;  // drain stray prefetches before LDS dealloc

  // ---- epilogue: 32x32 C/D layout: col=lane&31,
  //      row = (reg&3) + 8*(reg>>2) + 4*(lane>>5) ----
  const int rbase = bm + wm * 128 + 4 * (l >> 5);
#pragma unroll
  for (int nf = 0; nf < 2; ++nf) {
    const int col = bn + wn * 64 + nf * 32 + lc;
    const float bv = bias[col];
#pragma unroll
    for (int mf = 0; mf < 4; ++mf) {
#pragma unroll
      for (int reg = 0; reg < 16; ++reg) {
        const int row = rbase + mf * 32 + (reg & 3) + 8 * (reg >> 2);
        out[(size_t)row * NDIM + col] = acc[mf][nf][reg] + bv;
      }
    }
  }
}

extern "C" void kernel_launch(void* const* d_in, const int* in_sizes, int n_in,
                              void* d_out, int out_size, void* d_ws, size_t ws_size,
                              hipStream_t stream) {
  const float* x    = (const float*)d_in[0];
  const float* W    = (const float*)d_in[1];
  const float* bias = (const float*)d_in[2];
  const float* A    = (const float*)d_in[3];
  const float* B    = (const float*)d_in[4];
  float* out        = (float*)d_out;

  unsigned short* Wp = (unsigned short*)d_ws;                       // 32 MiB
  unsigned short* Xb = (unsigned short*)d_ws + (size_t)NDIM * KDIM; // 128 MiB

  prep_fused<<<dim3(CAST_BLOCKS + 8192), 256, 0, stream>>>(x, W, A, B, Xb, Wp);
  gemm256<<<dim3((MDIM / 256) * (NDIM / 256)), 512, 0, stream>>>(Xb, Wp, bias, out);
}

// Round 8
// 596.240 us; speedup vs baseline: 1.6301x; 1.1874x over previous
//
#include <hip/hip_runtime.h>
#include <stdint.h>

// out[b,s,o] = sum_i x[b,s,i] * (W[o,i] + sum_r A[o,r]*B[r,i]) + bias[o]
// M = 16384, N = 4096, K = 4096. fp32 in/out, bf16 MFMA compute.
// GEMM: 256x256 tile, BK=64, 8 waves, 8-phase schedule, 16x16x32 MFMA.
// R8: inline-asm ds_read_b128 (invisible to compiler waitcnt pass -> no
//     conservative vmcnt(0) before reads); manual lgkmcnt(0)+sched_barrier
//     per phase (rule #18); R5 stage schedule with vmcnt(8) at even phases.

#define MDIM 16384
#define NDIM 4096
#define KDIM 4096
#define RANK 16
#define NT   (KDIM / 64)   // 64 K-tiles

typedef __bf16  bf16x8 __attribute__((ext_vector_type(8)));
typedef float   f32x4  __attribute__((ext_vector_type(4)));
typedef unsigned short u16x8 __attribute__((ext_vector_type(8)));

__device__ __forceinline__ unsigned short f2bf(float f) {
  union { float f; uint32_t u; } v; v.f = f;
  uint32_t r = v.u + 0x7FFFu + ((v.u >> 16) & 1u);
  return (unsigned short)(r >> 16);
}

__device__ __forceinline__ void gl16(const void* g, void* l) {
  __builtin_amdgcn_global_load_lds(
      (__attribute__((address_space(1))) void*)(g),
      (__attribute__((address_space(3))) void*)(l),
      16, 0, 0);
}

// Fused prep: blocks [0, 32768) cast x fp32->bf16 (8 elems/thread);
//             blocks [32768, 40960) compute Wp = bf16(W + A@B).
#define CAST_BLOCKS 32768
__global__ void prep_fused(const float* __restrict__ x,
                           const float* __restrict__ W,
                           const float* __restrict__ A,
                           const float* __restrict__ Bm,
                           unsigned short* __restrict__ xb,
                           unsigned short* __restrict__ Wp) {
  const int b = blockIdx.x;
  if (b < CAST_BLOCKS) {
    const size_t i = ((size_t)b * 256 + threadIdx.x) * 8;
    float4 a0 = *(const float4*)(x + i);
    float4 a1 = *(const float4*)(x + i + 4);
    u16x8 o;
    o[0] = f2bf(a0.x); o[1] = f2bf(a0.y); o[2] = f2bf(a0.z); o[3] = f2bf(a0.w);
    o[4] = f2bf(a1.x); o[5] = f2bf(a1.y); o[6] = f2bf(a1.z); o[7] = f2bf(a1.w);
    *(u16x8*)(xb + i) = o;
  } else {
    const size_t idx = ((size_t)(b - CAST_BLOCKS) * 256 + threadIdx.x) * 8;
    const int o  = (int)(idx >> 12);
    const int i0 = (int)(idx & 4095);
    float accv[8];
    {
      float4 w0 = *(const float4*)(W + (size_t)o * NDIM + i0);
      float4 w1 = *(const float4*)(W + (size_t)o * NDIM + i0 + 4);
      accv[0] = w0.x; accv[1] = w0.y; accv[2] = w0.z; accv[3] = w0.w;
      accv[4] = w1.x; accv[5] = w1.y; accv[6] = w1.z; accv[7] = w1.w;
    }
#pragma unroll
    for (int r = 0; r < RANK; ++r) {
      const float ar = A[o * RANK + r];
      float4 b0 = *(const float4*)(Bm + (size_t)r * NDIM + i0);
      float4 b1 = *(const float4*)(Bm + (size_t)r * NDIM + i0 + 4);
      accv[0] += ar * b0.x; accv[1] += ar * b0.y;
      accv[2] += ar * b0.z; accv[3] += ar * b0.w;
      accv[4] += ar * b1.x; accv[5] += ar * b1.y;
      accv[6] += ar * b1.z; accv[7] += ar * b1.w;
    }
    u16x8 ov;
#pragma unroll
    for (int j = 0; j < 8; ++j) ov[j] = f2bf(accv[j]);
    *(u16x8*)(Wp + idx) = ov;
  }
}

#define BARRIER  __builtin_amdgcn_s_barrier()
#define VMCNT8   asm volatile("s_waitcnt vmcnt(8)" ::: "memory")
#define VMCNT6   asm volatile("s_waitcnt vmcnt(6)" ::: "memory")
#define WAITVM0  asm volatile("s_waitcnt vmcnt(0)" ::: "memory")
#define LGKM0    asm volatile("s_waitcnt lgkmcnt(0)" ::: "memory")
#define SCHEDB   __builtin_amdgcn_sched_barrier(0)

// inline-asm LDS read, compile-time byte offset immediate
#define DSR(dst, addr, imm)                                                   \
  asm volatile("ds_read_b128 %0, %1 offset:%c2"                               \
               : "=v"(dst) : "v"(addr), "n"(imm) : "memory")

// ---- staging (unchanged from R5): one half-tile = 2 x gl16 per thread ----
#define STAGE_A(buf, h, kt) do {                                              \
    const int kc_ = ((kt) < NT ? (kt) : NT - 1);                              \
    const unsigned short* g_ = agb + (size_t)((h) * 64) * KDIM + kc_ * 64;    \
    unsigned short* d_ = &sA[(buf)][0] + (h) * 8192 + t * 8;                  \
    gl16(g_, d_);                                                             \
    gl16(g_ + (size_t)128 * KDIM, d_ + 4096);                                 \
  } while (0)

#define STAGE_B(buf, h, kt) do {                                              \
    const int kc_ = ((kt) < NT ? (kt) : NT - 1);                              \
    const unsigned short* g_ = bgb + (size_t)((h) * 32) * KDIM + kc_ * 64;    \
    unsigned short* d_ = &sB[(buf)][0] + (h) * 8192 + t * 8;                  \
    gl16(g_, d_);                                                             \
    gl16(g_ + (size_t)128 * KDIM, d_ + 4096);                                 \
  } while (0)

// A fragments: row = buf | mh*128 + wm*64 + mi*16 + lr, kk selects addr reg.
#define LDA(buf, mh) do {                                                     \
    DSR(a[0][0], aAddr0, (buf)*32768 + (mh)*16384 + 0);                       \
    DSR(a[0][1], aAddr1, (buf)*32768 + (mh)*16384 + 0);                       \
    DSR(a[1][0], aAddr0, (buf)*32768 + (mh)*16384 + 2048);                    \
    DSR(a[1][1], aAddr1, (buf)*32768 + (mh)*16384 + 2048);                    \
    DSR(a[2][0], aAddr0, (buf)*32768 + (mh)*16384 + 4096);                    \
    DSR(a[2][1], aAddr1, (buf)*32768 + (mh)*16384 + 4096);                    \
    DSR(a[3][0], aAddr0, (buf)*32768 + (mh)*16384 + 6144);                    \
    DSR(a[3][1], aAddr1, (buf)*32768 + (mh)*16384 + 6144);                    \
  } while (0)

// B fragments: row = buf | nh*128 + wn*32 + ni*16 + lr.
#define LDB(bb, buf, nh) do {                                                 \
    DSR(bb[0][0], bAddr0, (buf)*32768 + (nh)*16384 + 0);                      \
    DSR(bb[0][1], bAddr1, (buf)*32768 + (nh)*16384 + 0);                      \
    DSR(bb[1][0], bAddr0, (buf)*32768 + (nh)*16384 + 2048);                   \
    DSR(bb[1][1], bAddr1, (buf)*32768 + (nh)*16384 + 2048);                   \
  } while (0)

#define MM(mh, nh, bb) do {                                                   \
    __builtin_amdgcn_s_setprio(1);                                            \
    _Pragma("unroll") for (int mi = 0; mi < 4; ++mi)                          \
    _Pragma("unroll") for (int ni = 0; ni < 2; ++ni)                          \
    _Pragma("unroll") for (int kk = 0; kk < 2; ++kk)                          \
      acc[(mh)*4+mi][(nh)*2+ni] = __builtin_amdgcn_mfma_f32_16x16x32_bf16(    \
          a[mi][kk], bb[ni][kk], acc[(mh)*4+mi][(nh)*2+ni], 0, 0, 0);         \
    __builtin_amdgcn_s_setprio(0);                                            \
  } while (0)

__global__ __launch_bounds__(512, 2) void gemm256(
    const unsigned short* __restrict__ Xb,
    const unsigned short* __restrict__ Wp,
    const float* __restrict__ bias,
    float* __restrict__ out) {
  __shared__ __align__(16) unsigned short sA[2][256 * 64];  // 64 KiB
  __shared__ __align__(16) unsigned short sB[2][256 * 64];  // 64 KiB

  const int t  = threadIdx.x;
  const int l  = t & 63;
  const int w  = t >> 6;   // 0..7
  const int wm = w >> 2;   // 0..1  (m half: 128 rows)
  const int wn = w & 3;    // 0..3  (n quarter: 64 cols)

  // XCD-aware bijective swizzle; n-fastest: each XCD owns an 8-row bm band.
  const int bid = blockIdx.x;
  const int swz = (bid & 7) * (1024 / 8) + (bid >> 3);
  const int bm  = (swz >> 4) * 256;   // 64 m-tiles
  const int bn  = (swz & 15) * 256;   // 16 n-tiles

  // ---- staging bases ----
  const int sr  = t >> 3;  // LDS-row-within-half 0..63
  const int ske = (((t & 7) * 16) ^ ((sr & 7) << 4)) >> 1;  // bytes -> elems
  const unsigned short* agb = Xb + (size_t)(bm + sr) * KDIM + ske;
  const unsigned short* bgb = Wp + (size_t)(bn + (sr >> 5) * 64 + (sr & 31)) * KDIM + ske;

  // ---- ds_read address registers (loop-invariant; low 32 bits of generic
  //      shared pointer = LDS byte offset) ----
  const int lr   = l & 15;
  const int koff = (l >> 4) * 8;      // elements
  const int xorE = (lr & 7) << 3;     // elements ((row&7)<<4 bytes)
  const unsigned ldsA = (unsigned)(uintptr_t)&sA[0][0];
  const unsigned ldsB = (unsigned)(uintptr_t)&sB[0][0];
  const unsigned aAddr0 = ldsA + (unsigned)((wm * 64 + lr) * 128 + ((koff ^ xorE) * 2));
  const unsigned aAddr1 = ldsA + (unsigned)((wm * 64 + lr) * 128 + (((32 + koff) ^ xorE) * 2));
  const unsigned bAddr0 = ldsB + (unsigned)((wn * 32 + lr) * 128 + ((koff ^ xorE) * 2));
  const unsigned bAddr1 = ldsB + (unsigned)((wn * 32 + lr) * 128 + (((32 + koff) ^ xorE) * 2));

  bf16x8 a[4][2], b0[2][2], b1[2][2];
  f32x4 acc[8][4];
#pragma unroll
  for (int i = 0; i < 8; ++i)
#pragma unroll
    for (int j = 0; j < 4; ++j)
      acc[i][j] = f32x4{0.f, 0.f, 0.f, 0.f};

  // ---- prologue: tile0 all 4 halves + tile1 {A.h0,B.h0,B.h1} (14 loads);
  //      vmcnt(6) -> tile0 fully landed, tile1's 3 halves in flight.
  STAGE_A(0, 0, 0); STAGE_B(0, 0, 0); STAGE_A(0, 1, 0); STAGE_B(0, 1, 0);
  STAGE_A(1, 0, 1); STAGE_B(1, 0, 1); STAGE_B(1, 1, 1);
  VMCNT6;
  BARRIER;

  // ---- main loop: 2 K-tiles / iter, 8 phases; stage slots 6-7 phases ahead:
  // ph1: b1.A.h1<-E+1 | ph2: b0.A.h0<-E+2 | ph3: b0.B.h0 | ph4: b0.B.h1
  // ph5: b0.A.h1      | ph6: b1.A.h0<-E+3 | ph7: b1.B.h0 | ph8: b1.B.h1
  for (int it = 0; it < NT / 2; ++it) {
    const int E = it * 2;
    // ph1 (buf0): quadrant 00
    LDA(0, 0); LDB(b0, 0, 0);
    STAGE_A(1, 1, E + 1);
    BARRIER; LGKM0; SCHEDB;
    MM(0, 0, b0);
    BARRIER;
    // ph2: quadrant 01
    LDB(b1, 0, 1);
    STAGE_A(0, 0, E + 2);
    BARRIER; LGKM0; SCHEDB;
    MM(0, 1, b1);
    VMCNT8;
    BARRIER;
    // ph3: quadrant 11
    LDA(0, 1);
    STAGE_B(0, 0, E + 2);
    BARRIER; LGKM0; SCHEDB;
    MM(1, 1, b1);
    BARRIER;
    // ph4: quadrant 10 (no ds_read)
    STAGE_B(0, 1, E + 2);
    BARRIER;
    MM(1, 0, b0);
    VMCNT8;
    BARRIER;
    // ph5 (buf1): quadrant 00
    LDA(1, 0); LDB(b0, 1, 0);
    STAGE_A(0, 1, E + 2);
    BARRIER; LGKM0; SCHEDB;
    MM(0, 0, b0);
    BARRIER;
    // ph6: quadrant 01
    LDB(b1, 1, 1);
    STAGE_A(1, 0, E + 3);
    BARRIER; LGKM0; SCHEDB;
    MM(0, 1, b1);
    VMCNT8;
    BARRIER;
    // ph7: quadrant 11
    LDA(1, 1);
    STAGE_B(1, 0, E + 3);
    BARRIER; LGKM0; SCHEDB;
    MM(1, 1, b1);
    BARRIER;
    // ph8: quadrant 10
    STAGE_B(1, 1, E + 3);
    BARRIER;
    MM(1, 0, b0);
    VMCNT8;
    BARRIER;
  }

  WAITVM0;  // drain stray prefetches before exit

  // ---- epilogue: C/D layout col=lane&15, row=(lane>>4)*4+reg ----
#pragma unroll
  for (int mf = 0; mf < 8; ++mf) {
#pragma unroll
    for (int nf = 0; nf < 4; ++nf) {
      const int row = bm + wm * 128 + mf * 16 + (l >> 4) * 4;
      const int col = bn + wn * 64 + nf * 16 + lr;
      const float bv = bias[col];
#pragma unroll
      for (int r = 0; r < 4; ++r)
        out[(size_t)(row + r) * NDIM + col] = acc[mf][nf][r] + bv;
    }
  }
}

extern "C" void kernel_launch(void* const* d_in, const int* in_sizes, int n_in,
                              void* d_out, int out_size, void* d_ws, size_t ws_size,
                              hipStream_t stream) {
  const float* x    = (const float*)d_in[0];
  const float* W    = (const float*)d_in[1];
  const float* bias = (const float*)d_in[2];
  const float* A    = (const float*)d_in[3];
  const float* B    = (const float*)d_in[4];
  float* out        = (float*)d_out;

  unsigned short* Wp = (unsigned short*)d_ws;                       // 32 MiB
  unsigned short* Xb = (unsigned short*)d_ws + (size_t)NDIM * KDIM; // 128 MiB

  prep_fused<<<dim3(CAST_BLOCKS + 8192), 256, 0, stream>>>(x, W, A, B, Xb, Wp);
  gemm256<<<dim3((MDIM / 256) * (NDIM / 256)), 512, 0, stream>>>(Xb, Wp, bias, out);
}